// Round 11
// baseline (192.377 us; speedup 1.0000x reference)
//
#include <hip/hip_runtime.h>
#include <hip/hip_cooperative_groups.h>
#include <hip/hip_bf16.h>
#include <stdint.h>

namespace cg = cooperative_groups;

#define NCLS 10
#define B_ 8
#define N_ 16384
#define G_ 64
#define INF_ 1.0e8f

typedef unsigned long long u64;
typedef unsigned int u32;

__device__ __forceinline__ u32 ordf(float f) {
    u32 b = __float_as_uint(f);
    return (b & 0x80000000u) ? ~b : (b | 0x80000000u);
}
__device__ __forceinline__ float unordf(u32 u) {
    u32 b = (u & 0x80000000u) ? (u ^ 0x80000000u) : ~u;
    return __uint_as_float(b);
}

// Op-for-op identical to the validated round-1 eval (contract off).
__device__ __forceinline__ float iou_pair(float px, float pz, float g3x, float g3z) {
#pragma clang fp contract(off)
    float ddx = px - g3x;
    float ddz = pz - g3z;
    float d = sqrtf(ddx * ddx + ddz * ddz);
    float iou = 1.0f - d / 4.0f;
    return fminf(fmaxf(iou, 0.0f), 1.0f);
}

// Cost for an INSIDE pair (is_in == pad > 0). Identical op order to round 1.
__device__ __forceinline__ float cost_pair(float cx, float cy, float sx, float sy,
                                           float ps, float gcx, float gcy,
                                           float pad, float iou) {
#pragma clang fp contract(off)
    float dx = (cx - gcx) / sx;
    float dy = (cy - gcy) / sy;
    float dist = sqrtf(dx * dx + dy * dy) * pad;
    float soft = exp10f(dist - 3.0f);
    float iou_cost = -logf(iou + 1e-7f) * 3.0f;
    float e = expf(-fabsf(ps));
    float sig = (ps >= 0.0f) ? (1.0f / (1.0f + e)) : (e / (1.0f + e));
    float scale = iou - sig;
    float bce = fmaxf(ps, 0.0f) - ps * iou + log1pf(e);
    float cls = bce * (scale * scale);
    return cls + iou_cost + soft;
}

__device__ __forceinline__ u32 wave_max_u32(u32 k) {
#pragma unroll
    for (int off = 32; off >= 1; off >>= 1) {
        u32 o = __shfl_xor(k, off, 64);
        k = (o > k) ? o : k;
    }
    return k;
}
__device__ __forceinline__ u32 wave_min_u32(u32 k) {
#pragma unroll
    for (int off = 32; off >= 1; off >>= 1) {
        u32 o = __shfl_xor(k, off, 64);
        k = (o < k) ? o : k;
    }
    return k;
}

#define CSWAPD(a, b) { float _h = fmaxf(a, b), _l = fminf(a, b); a = _h; b = _l; }

// Single cooperative kernel: A(mask/bitmap/pack) |grid| B(iou partials, LDS)
// + C(ks + threshold) |grid| D(matching + output).
__global__ __launch_bounds__(256) void kfused(
    const float* __restrict__ pred_bboxes,
    const float* __restrict__ pred_scores,
    const float* __restrict__ priors,
    const int*   __restrict__ gt_labels,
    const float* __restrict__ gt_bboxes,
    const float* __restrict__ gt_center,
    const float* __restrict__ gt_b3d,
    const float* __restrict__ pad_flag,
    u64* __restrict__ mask64,
    u64* __restrict__ bitmapT,
    float2* __restrict__ pxz,
    float* __restrict__ thr_half,
    float* __restrict__ out)
{
    cg::grid_group grid = cg::this_grid();

    __shared__ float s_part[416];               // 32 chunks x 13 iou partials
    __shared__ float s_i[52], s_c[56];
    __shared__ float s_gcx[G_], s_gcy[G_], s_g3x[G_], s_g3z[G_];
    __shared__ float s_pad[G_], s_thr[G_];
    __shared__ int   s_lab[G_];
    __shared__ u64   s_words[256];

    int tid = threadIdx.x;
    int lane = tid & 63;
    int w = tid >> 6;
    int q = blockIdx.x;                         // 0..511
    int b = q >> 6;
    int nsl = ((q & 63) << 8) | tid;            // this block's prior slice elem
    size_t t = (size_t)b * N_ + nsl;

    // ================= Phase A: mask + bitmapT + pxz =================
    {
        u32 wword = ((q & 63) << 2) | (u32)w;   // word index 0..255
        float4 pr = ((const float4*)priors)[nsl];
        float cx = pr.x, cy = pr.y;
        u64 m = 0;
        for (int g = 0; g < G_; ++g) {
            int gi = b * G_ + g;                // uniform
            float4 gbb = ((const float4*)gt_bboxes)[gi];
            float padv = pad_flag[gi];
            bool isin = (cx > gbb.x) && (cy > gbb.y) && (cx < gbb.z) && (cy < gbb.w)
                        && (padv > 0.0f);
            m |= ((u64)isin) << g;
            u64 bal = __ballot(isin);
            if (lane == 0) bitmapT[(((size_t)gi) << 8) | wword] = bal;
        }
        mask64[t] = m;
        float2 v;
        v.x = pred_bboxes[t * 7 + 0];
        v.y = pred_bboxes[t * 7 + 2];
        pxz[t] = v;
    }
    grid.sync();

    // ================= Phase B: iou top-13 partials (block == gi) ====
    int gi = q;
    float g3x = gt_b3d[gi * 7 + 0];
    float g3z = gt_b3d[gi * 7 + 2];
    const float2* pp = pxz + (size_t)b * N_;
    for (int c8 = 0; c8 < 8; ++c8) {
        int chunk = w * 8 + c8;
        const float2* p0 = pp + (size_t)(chunk * 512 + lane);
        float2 e0 = p0[0],   e1 = p0[64],  e2 = p0[128], e3 = p0[192];
        float2 e4 = p0[256], e5 = p0[320], e6 = p0[384], e7 = p0[448];
        float s0 = iou_pair(e0.x, e0.y, g3x, g3z);
        float s1 = iou_pair(e1.x, e1.y, g3x, g3z);
        float s2 = iou_pair(e2.x, e2.y, g3x, g3z);
        float s3 = iou_pair(e3.x, e3.y, g3x, g3z);
        float s4 = iou_pair(e4.x, e4.y, g3x, g3z);
        float s5 = iou_pair(e5.x, e5.y, g3x, g3z);
        float s6 = iou_pair(e6.x, e6.y, g3x, g3z);
        float s7 = iou_pair(e7.x, e7.y, g3x, g3z);
        // Batcher odd-even mergesort, 8 elems, descending (19 comparators).
        CSWAPD(s0, s1) CSWAPD(s2, s3) CSWAPD(s4, s5) CSWAPD(s6, s7)
        CSWAPD(s0, s2) CSWAPD(s1, s3) CSWAPD(s4, s6) CSWAPD(s5, s7)
        CSWAPD(s1, s2) CSWAPD(s5, s6)
        CSWAPD(s0, s4) CSWAPD(s1, s5) CSWAPD(s2, s6) CSWAPD(s3, s7)
        CSWAPD(s2, s4) CSWAPD(s3, s5)
        CSWAPD(s1, s2) CSWAPD(s3, s4) CSWAPD(s5, s6)
        // 13-round extraction: u32 key, ballot winner (lowest lane on tie).
        float keepv = 0.0f;
        for (int r = 0; r < 13; ++r) {
            u32 mykey = ordf(s0);
            u32 m = wave_max_u32(mykey);
            if (lane == r) keepv = unordf(m);
            int winner = __ffsll(__ballot(mykey == m)) - 1;
            bool win = (lane == winner);
            s0 = win ? s1 : s0;
            s1 = win ? s2 : s1;
            s2 = win ? s3 : s2;
            s3 = win ? s4 : s3;
            s4 = win ? s5 : s4;
            s5 = win ? s6 : s5;
            s6 = win ? s7 : s6;
            s7 = win ? -3.0e38f : s7;
        }
        if (lane < 13) s_part[chunk * 13 + lane] = keepv;
    }
    __syncthreads();

    // ================= Phase C: ks + threshold =======================
    // (i) per-wave merge of its 104 iou partials (8 sorted-desc runs)
    {
        const float* basep = s_part + w * 104;
        float v0 = basep[lane];
        float v1 = (lane < 40) ? basep[64 + lane] : -3.0e38f;
        if (v1 > v0) { float tt = v0; v0 = v1; v1 = tt; }
        float keepv = 0.0f;
        for (int r = 0; r < 13; ++r) {
            u32 mykey = ordf(v0);
            u32 m = wave_max_u32(mykey);
            if (lane == r) keepv = unordf(m);
            int winner = __ffsll(__ballot(mykey == m)) - 1;
            if (lane == winner) { v0 = v1; v1 = -3.0e38f; }
        }
        if (lane < 13) s_i[w * 13 + lane] = keepv;
    }
    // (ii) per-thread cost scan of bitmap word tid; per-wave bottom-14
    {
        float gcx = gt_center[gi * 2 + 0], gcy = gt_center[gi * 2 + 1];
        float padv = pad_flag[gi];
        int lab = gt_labels[gi];
        const float* sc = pred_scores + (size_t)b * N_ * 10;

        float l[14];
#pragma unroll
        for (int j = 0; j < 14; ++j) l[j] = INF_;
        u64 wv = bitmapT[(((size_t)gi) << 8) | (u32)tid];
        u32 nb = (u32)tid << 6;
        while (wv) {
            int bit = __ffsll(wv) - 1;
            wv &= wv - 1;
            int n = (int)(nb | (u32)bit);
            float4 pr = ((const float4*)priors)[n];
            float2 v = pp[n];
            float ps = sc[n * 10 + lab];
            float iou = iou_pair(v.x, v.y, g3x, g3z);
            float cst = cost_pair(pr.x, pr.y, pr.z, pr.w, ps, gcx, gcy, padv, iou);
            if (cst < l[13]) {
                float vv = cst;
#pragma unroll
                for (int jj = 0; jj < 14; ++jj) {
                    float o = l[jj]; bool lt = vv < o;
                    float mn = lt ? vv : o; vv = lt ? o : vv; l[jj] = mn;
                }
            }
        }
        float keepc = 0.0f;
        for (int r = 0; r < 14; ++r) {
            u32 mykey = ordf(l[0]);
            u32 m = wave_min_u32(mykey);
            if (lane == r) keepc = unordf(m);
            int winner = __ffsll(__ballot(mykey == m)) - 1;
            if (lane == winner) {
#pragma unroll
                for (int j = 0; j < 13; ++j) l[j] = l[j + 1];
                l[13] = 3.0e38f;
            }
        }
        if (lane < 14) s_c[w * 14 + lane] = keepc;
    }
    __syncthreads();

    if (w == 0) {
        // merge 52 iou partials -> ks (descending-order sum)
        float vi = (lane < 52) ? s_i[lane] : -3.0e38f;
        float sum13 = 0.0f;
        for (int r = 0; r < 13; ++r) {
            u32 mykey = ordf(vi);
            u32 m = wave_max_u32(mykey);
            sum13 += unordf(m);
            int winner = __ffsll(__ballot(mykey == m)) - 1;
            if (lane == winner) vi = -3.0e38f;
        }
        int ks = (int)sum13;
        if (ks < 1) ks = 1;

        // merge 56 cost partials -> ck, ckm1
        float vc = (lane < 56) ? s_c[lane] : 3.0e38f;
        float ck = INF_, ckm1 = INF_;
        for (int r = 0; r < 14; ++r) {
            u32 mykey = ordf(vc);
            u32 m = wave_min_u32(mykey);
            float vm = unordf(m);
            if (r == ks - 1) ckm1 = vm;
            if (r == ks)     ck = vm;
            int winner = __ffsll(__ballot(mykey == m)) - 1;
            if (lane == winner) vc = 3.0e38f;
        }
        if (lane == 0) thr_half[gi] = 0.5f * (ck + ckm1);
    }
    grid.sync();

    // ================= Phase D: matching + output ====================
    if (tid < G_) {
        int gg = b * G_ + tid;
        s_gcx[tid] = gt_center[gg * 2 + 0];
        s_gcy[tid] = gt_center[gg * 2 + 1];
        s_g3x[tid] = gt_b3d[gg * 7 + 0];
        s_g3z[tid] = gt_b3d[gg * 7 + 2];
        s_pad[tid] = pad_flag[gg];
        s_thr[tid] = thr_half[gg];
        s_lab[tid] = gt_labels[gg];
    }
    __syncthreads();

    {
        const float* sc = pred_scores + (size_t)b * N_ * 10;
        float4 pr = ((const float4*)priors)[nsl];
        float2 v2p = pxz[t];
        float px = v2p.x;
        float pz = v2p.y;

        // init = g 0 (argmin over all-INF costs returns index 0)
        float iouC = iou_pair(px, pz, s_g3x[0], s_g3z[0]);
        float costC = INF_;
        int   labC = s_lab[0];

        float iouM = 0.0f, costM = 3.0e38f;
        int   labM = 0, argM = 0;
        u64 mmatch = 0;

        u64 m = mask64[t];
        while (m) {
            int g = __ffsll(m) - 1;
            m &= m - 1;
            float gcx = s_gcx[g], gcy = s_gcy[g];
            float g3xx = s_g3x[g], g3zz = s_g3z[g];
            float padg = s_pad[g];
            int   labg = s_lab[g];
            float th = s_thr[g];
            float ps = sc[nsl * 10 + labg];
            float iou = iou_pair(px, pz, g3xx, g3zz);
            float c = cost_pair(pr.x, pr.y, pr.z, pr.w, ps, gcx, gcy, padg, iou);
            if (c < costC) { costC = c; iouC = iou; labC = labg; }
            if (c <= th * padg) {
                mmatch |= 1ull << g;
                if (c < costM) { costM = c; iouM = iou; labM = labg; argM = g; }
            }
        }
        int cm = __popcll(mmatch);
        bool matched = cm > 0;
        u64 outm = (cm > 1) ? (1ull << argM) : mmatch;
        float metric = matched ? iouM : iouC;
        float olab = matched ? (float)labM
                             : ((iouC < 1e-7f) ? (float)NCLS : (float)labC);

        float* out_lab = out;
        float* out_w   = out + (size_t)B_ * N_;
        float* out_met = out + (size_t)2 * B_ * N_;
        float* out_mat = out + (size_t)3 * B_ * N_;
        out_lab[t] = olab;
        out_w[t]   = 1.0f;
        out_met[t] = metric;
        s_words[tid] = outm;
    }
    __syncthreads();

    // expand 256 words -> 256 rows x 64 floats, coalesced float4 stores
    {
        float* out_mat = out + (size_t)3 * B_ * N_;
        int qq = tid & 3;                      // 16-col quarter
        int r0 = tid >> 2;                     // base row 0..63
        size_t rowbase = (size_t)b * N_ + ((q & 63) << 8);
#pragma unroll
        for (int it = 0; it < 4; ++it) {
            int row = r0 + (it << 6);
            u64 wv = s_words[row];
            u32 bits = (u32)(wv >> (qq * 16)) & 0xffffu;
            float* dst = out_mat + (rowbase + row) * 64 + qq * 16;
#pragma unroll
            for (int jj = 0; jj < 4; ++jj) {
                float4 f;
                f.x = (bits >> (jj * 4 + 0)) & 1u ? 1.0f : 0.0f;
                f.y = (bits >> (jj * 4 + 1)) & 1u ? 1.0f : 0.0f;
                f.z = (bits >> (jj * 4 + 2)) & 1u ? 1.0f : 0.0f;
                f.w = (bits >> (jj * 4 + 3)) & 1u ? 1.0f : 0.0f;
                ((float4*)dst)[jj] = f;
            }
        }
    }
}

extern "C" void kernel_launch(void* const* d_in, const int* in_sizes, int n_in,
                              void* d_out, int out_size, void* d_ws, size_t ws_size,
                              hipStream_t stream)
{
    const float* pred_bboxes = (const float*)d_in[0];
    const float* pred_scores = (const float*)d_in[1];
    const float* priors      = (const float*)d_in[2];
    const int*   gt_labels   = (const int*)d_in[3];
    const float* gt_bboxes   = (const float*)d_in[4];
    const float* gt_center   = (const float*)d_in[5];
    const float* gt_b3d      = (const float*)d_in[6];
    const float* pad_flag    = (const float*)d_in[7];
    float* out = (float*)d_out;

    // ws layout (bytes):
    char* ws = (char*)d_ws;
    u64* mask64   = (u64*)ws;                              // 131072*8 = 1048576
    u64* bitmapT  = (u64*)(ws + 1048576);                  // 512*256*8 = 1048576
    float2* pxz   = (float2*)(ws + 2097152);               // 131072*8 = 1048576
    float* thr_half = (float*)(ws + 3145728);              // 512*4

    void* args[] = {
        (void*)&pred_bboxes, (void*)&pred_scores, (void*)&priors,
        (void*)&gt_labels, (void*)&gt_bboxes, (void*)&gt_center,
        (void*)&gt_b3d, (void*)&pad_flag,
        (void*)&mask64, (void*)&bitmapT, (void*)&pxz, (void*)&thr_half,
        (void*)&out
    };
    hipLaunchCooperativeKernel((const void*)kfused, dim3(512), dim3(256),
                               args, 0, stream);
}

// Round 12
// 82.450 us; speedup vs baseline: 2.3333x; 2.3333x over previous
//
#include <hip/hip_runtime.h>
#include <hip/hip_bf16.h>
#include <stdint.h>

#define NCLS 10
#define B_ 8
#define N_ 16384
#define G_ 64
#define INF_ 1.0e8f

typedef unsigned long long u64;
typedef unsigned int u32;

__device__ __forceinline__ u32 ordf(float f) {
    u32 b = __float_as_uint(f);
    return (b & 0x80000000u) ? ~b : (b | 0x80000000u);
}
__device__ __forceinline__ float unordf(u32 u) {
    u32 b = (u & 0x80000000u) ? (u ^ 0x80000000u) : ~u;
    return __uint_as_float(b);
}

// Op-for-op identical to the validated round-1 eval (contract off).
__device__ __forceinline__ float iou_pair(float px, float pz, float g3x, float g3z) {
#pragma clang fp contract(off)
    float ddx = px - g3x;
    float ddz = pz - g3z;
    float d = sqrtf(ddx * ddx + ddz * ddz);
    float iou = 1.0f - d / 4.0f;
    return fminf(fmaxf(iou, 0.0f), 1.0f);
}

// Cost for an INSIDE pair (is_in == pad > 0). Identical op order to round 1.
__device__ __forceinline__ float cost_pair(float cx, float cy, float sx, float sy,
                                           float ps, float gcx, float gcy,
                                           float pad, float iou) {
#pragma clang fp contract(off)
    float dx = (cx - gcx) / sx;
    float dy = (cy - gcy) / sy;
    float dist = sqrtf(dx * dx + dy * dy) * pad;
    float soft = exp10f(dist - 3.0f);
    float iou_cost = -logf(iou + 1e-7f) * 3.0f;
    float e = expf(-fabsf(ps));
    float sig = (ps >= 0.0f) ? (1.0f / (1.0f + e)) : (e / (1.0f + e));
    float scale = iou - sig;
    float bce = fmaxf(ps, 0.0f) - ps * iou + log1pf(e);
    float cls = bce * (scale * scale);
    return cls + iou_cost + soft;
}

__device__ __forceinline__ u32 wave_max_u32(u32 k) {
#pragma unroll
    for (int off = 32; off >= 1; off >>= 1) {
        u32 o = __shfl_xor(k, off, 64);
        k = (o > k) ? o : k;
    }
    return k;
}
__device__ __forceinline__ u32 wave_min_u32(u32 k) {
#pragma unroll
    for (int off = 32; off >= 1; off >>= 1) {
        u32 o = __shfl_xor(k, off, 64);
        k = (o < k) ? o : k;
    }
    return k;
}

// ---------------- kP: mask+bitmapT (blocks 0..511) + pxz pack (512..575) ---
// Mask role: per-g ballot accumulated into a per-lane register via cndmask
// (no exec-masked store in the loop), then ONE coalesced wave-wide store.
// bitmapT layout: [word][gi] so lane==gi stores are consecutive u64.
__global__ __launch_bounds__(256) void kP(
    const float* __restrict__ priors,
    const float* __restrict__ gt_bboxes,
    const float* __restrict__ pad_flag,
    const float* __restrict__ pred_bboxes,
    u64* __restrict__ mask64,
    u64* __restrict__ bitmapT,
    float2* __restrict__ pxz)
{
    int tid = threadIdx.x;
    int lane = tid & 63;
    if (blockIdx.x < 512) {
        int q = blockIdx.x;
        int b = q >> 6;
        int n = ((q & 63) << 8) | tid;
        u32 wword = ((q & 63) << 2) | (u32)(tid >> 6);   // word index 0..255
        float4 pr = ((const float4*)priors)[n];
        float cx = pr.x, cy = pr.y;
        u64 m = 0;
        u64 myword = 0;
        for (int g = 0; g < G_; ++g) {
            int gi = b * G_ + g;                  // uniform
            float4 gbb = ((const float4*)gt_bboxes)[gi];
            float padv = pad_flag[gi];
            bool isin = (cx > gbb.x) && (cy > gbb.y) && (cx < gbb.z) && (cy < gbb.w)
                        && (padv > 0.0f);
            m |= ((u64)isin) << g;
            u64 bal = __ballot(isin);
            if (lane == g) myword = bal;          // cndmask, no store
        }
        mask64[(size_t)b * N_ + n] = m;
        // coalesced: lane l -> gi = b*64+l for word wword
        bitmapT[(size_t)wword * 512 + (size_t)(b * G_ + lane)] = myword;
    } else {
        // ------- pxz pack role: 64 blocks x 256 thr x 8 elems -------
        int base = (int)(blockIdx.x - 512) * 2048 + tid;
#pragma unroll
        for (int i = 0; i < 8; ++i) {
            int idx = base + i * 256;             // 0 .. B*N-1
            float2 v;
            v.x = pred_bboxes[(size_t)idx * 7 + 0];
            v.y = pred_bboxes[(size_t)idx * 7 + 2];
            pxz[idx] = v;
        }
    }
}

#define CSWAPD(a, b) { float _h = fmaxf(a, b), _l = fminf(a, b); a = _h; b = _l; }

// ---------------- k1b: per-(b,g,chunk of 512) iou top-13 partials ---------
// (verbatim round-10: named registers, Batcher-8, 13-round extraction)
__global__ __launch_bounds__(256) void k1b(
    const float2* __restrict__ pxz,
    const float* __restrict__ gt_b3d,
    float* __restrict__ iou13)
{
    int wid = ((int)blockIdx.x << 2) | (threadIdx.x >> 6);  // 0..16383
    int lane = threadIdx.x & 63;
    int b = wid >> 11;            // 2048 waves per batch
    int g = (wid >> 5) & 63;
    int chunk = wid & 31;
    int gi = b * G_ + g;
    float g3x = gt_b3d[gi * 7 + 0];
    float g3z = gt_b3d[gi * 7 + 2];
    const float2* pp = pxz + (size_t)b * N_ + (size_t)(chunk * 512 + lane);

    float2 e0 = pp[0],   e1 = pp[64],  e2 = pp[128], e3 = pp[192];
    float2 e4 = pp[256], e5 = pp[320], e6 = pp[384], e7 = pp[448];
    float s0 = iou_pair(e0.x, e0.y, g3x, g3z);
    float s1 = iou_pair(e1.x, e1.y, g3x, g3z);
    float s2 = iou_pair(e2.x, e2.y, g3x, g3z);
    float s3 = iou_pair(e3.x, e3.y, g3x, g3z);
    float s4 = iou_pair(e4.x, e4.y, g3x, g3z);
    float s5 = iou_pair(e5.x, e5.y, g3x, g3z);
    float s6 = iou_pair(e6.x, e6.y, g3x, g3z);
    float s7 = iou_pair(e7.x, e7.y, g3x, g3z);

    // Batcher odd-even mergesort, 8 elems, descending (19 comparators).
    CSWAPD(s0, s1) CSWAPD(s2, s3) CSWAPD(s4, s5) CSWAPD(s6, s7)
    CSWAPD(s0, s2) CSWAPD(s1, s3) CSWAPD(s4, s6) CSWAPD(s5, s7)
    CSWAPD(s1, s2) CSWAPD(s5, s6)
    CSWAPD(s0, s4) CSWAPD(s1, s5) CSWAPD(s2, s6) CSWAPD(s3, s7)
    CSWAPD(s2, s4) CSWAPD(s3, s5)
    CSWAPD(s1, s2) CSWAPD(s3, s4) CSWAPD(s5, s6)

    // 13-round extraction: u32 key, ballot winner (lowest lane on tie).
    float keepv = 0.0f;
    for (int r = 0; r < 13; ++r) {
        u32 mykey = ordf(s0);
        u32 m = wave_max_u32(mykey);
        if (lane == r) keepv = unordf(m);
        int winner = __ffsll(__ballot(mykey == m)) - 1;
        bool win = (lane == winner);
        s0 = win ? s1 : s0;
        s1 = win ? s2 : s1;
        s2 = win ? s3 : s2;
        s3 = win ? s4 : s3;
        s4 = win ? s5 : s4;
        s5 = win ? s6 : s5;
        s6 = win ? s7 : s6;
        s7 = win ? -3.0e38f : s7;
    }
    if (lane < 13) iou13[(size_t)gi * 416 + chunk * 13 + lane] = keepv;
}

// ---------------- k1c: per-(b,g) finalize, 4 waves/block -------------------
// (round-10 logic; only the bitmapT index changes to the [word][gi] layout)
__global__ __launch_bounds__(256) void k1c(
    const float* __restrict__ iou13,
    const u64*   __restrict__ bitmapT,
    const float* __restrict__ priors,
    const float2* __restrict__ pxz,
    const float* __restrict__ pred_scores,
    const int*   __restrict__ gt_labels,
    const float* __restrict__ gt_center,
    const float* __restrict__ gt_b3d,
    const float* __restrict__ pad_flag,
    float* __restrict__ thr_half)
{
    __shared__ float s_i[4 * 13];
    __shared__ float s_c[4 * 14];
    int gi = blockIdx.x;
    int b = gi >> 6;
    int lane = threadIdx.x & 63;
    int w = threadIdx.x >> 6;

    // (i) per-wave iou merge over its 104 partials (all sorted-desc runs)
    const float* base = iou13 + (size_t)gi * 416 + w * 104;
    float v0 = base[lane];
    float v1 = (lane < 40) ? base[64 + lane] : -3.0e38f;
    if (v1 > v0) { float t = v0; v0 = v1; v1 = t; }
    {
        float keepv = 0.0f;
        for (int r = 0; r < 13; ++r) {
            u32 mykey = ordf(v0);
            u32 m = wave_max_u32(mykey);
            if (lane == r) keepv = unordf(m);
            int winner = __ffsll(__ballot(mykey == m)) - 1;
            if (lane == winner) { v0 = v1; v1 = -3.0e38f; }
        }
        if (lane < 13) s_i[w * 13 + lane] = keepv;
    }

    // (ii) per-wave cost scan over 64 bitmap words (1 per thread)
    float gcx = gt_center[gi * 2 + 0], gcy = gt_center[gi * 2 + 1];
    float g3x = gt_b3d[gi * 7 + 0],   g3z = gt_b3d[gi * 7 + 2];
    float padv = pad_flag[gi];
    int lab = gt_labels[gi];
    const float2* pp = pxz + (size_t)b * N_;
    const float* sc = pred_scores + (size_t)b * N_ * 10;

    float l[14];
#pragma unroll
    for (int j = 0; j < 14; ++j) l[j] = INF_;
    {
        u32 word = (u32)(w * 64 + lane);
        u64 wv = bitmapT[(size_t)word * 512 + gi];
        u32 nb = word << 6;
        while (wv) {
            int bit = __ffsll(wv) - 1;
            wv &= wv - 1;
            int n = (int)(nb | (u32)bit);
            float4 pr = ((const float4*)priors)[n];
            float2 v = pp[n];
            float ps = sc[n * 10 + lab];
            float iou = iou_pair(v.x, v.y, g3x, g3z);
            float cst = cost_pair(pr.x, pr.y, pr.z, pr.w, ps, gcx, gcy, padv, iou);
            if (cst < l[13]) {
                float vv = cst;
#pragma unroll
                for (int jj = 0; jj < 14; ++jj) {
                    float o = l[jj]; bool lt = vv < o;
                    float mn = lt ? vv : o; vv = lt ? o : vv; l[jj] = mn;
                }
            }
        }
    }
    {
        float keepc = 0.0f;
        for (int r = 0; r < 14; ++r) {
            u32 mykey = ordf(l[0]);
            u32 m = wave_min_u32(mykey);
            if (lane == r) keepc = unordf(m);
            int winner = __ffsll(__ballot(mykey == m)) - 1;
            if (lane == winner) {
#pragma unroll
                for (int j = 0; j < 13; ++j) l[j] = l[j + 1];
                l[13] = 3.0e38f;
            }
        }
        if (lane < 14) s_c[w * 14 + lane] = keepc;
    }
    __syncthreads();

    if (w == 0) {
        // merge 52 iou partials -> ks (descending-order sum)
        float vi = (lane < 52) ? s_i[lane] : -3.0e38f;
        float sum13 = 0.0f;
        for (int r = 0; r < 13; ++r) {
            u32 mykey = ordf(vi);
            u32 m = wave_max_u32(mykey);
            sum13 += unordf(m);
            int winner = __ffsll(__ballot(mykey == m)) - 1;
            if (lane == winner) vi = -3.0e38f;
        }
        int ks = (int)sum13;
        if (ks < 1) ks = 1;

        // merge 56 cost partials -> ck, ckm1
        float vc = (lane < 56) ? s_c[lane] : 3.0e38f;
        float ck = INF_, ckm1 = INF_;
        for (int r = 0; r < 14; ++r) {
            u32 mykey = ordf(vc);
            u32 m = wave_min_u32(mykey);
            float vm = unordf(m);
            if (r == ks - 1) ckm1 = vm;
            if (r == ks)     ck = vm;
            int winner = __ffsll(__ballot(mykey == m)) - 1;
            if (lane == winner) vc = 3.0e38f;
        }
        if (lane == 0) thr_half[gi] = 0.5f * (ck + ckm1);
    }
}

// ---------------- k2: matching compute + coalesced bit expansion ----------
// (verbatim round-10 passing version)
__global__ __launch_bounds__(256) void k2(
    const float* __restrict__ priors,
    const float2* __restrict__ pxz,
    const float* __restrict__ pred_scores,
    const int*   __restrict__ gt_labels,
    const float* __restrict__ gt_center,
    const float* __restrict__ gt_b3d,
    const float* __restrict__ pad_flag,
    const float* __restrict__ thr_half,
    const u64*   __restrict__ mask64,
    float* __restrict__ out)
{
    __shared__ float s_gcx[G_], s_gcy[G_], s_g3x[G_], s_g3z[G_];
    __shared__ float s_pad[G_], s_thr[G_];
    __shared__ int   s_lab[G_];
    __shared__ u64   s_words[256];

    int b = blockIdx.x >> 6;
    int n0b = (blockIdx.x & 63) << 8;          // first prior of this block
    int n = n0b | threadIdx.x;
    size_t t = (size_t)b * N_ + n;

    if (threadIdx.x < G_) {
        int gi = b * G_ + threadIdx.x;
        s_gcx[threadIdx.x] = gt_center[gi * 2 + 0];
        s_gcy[threadIdx.x] = gt_center[gi * 2 + 1];
        s_g3x[threadIdx.x] = gt_b3d[gi * 7 + 0];
        s_g3z[threadIdx.x] = gt_b3d[gi * 7 + 2];
        s_pad[threadIdx.x] = pad_flag[gi];
        s_thr[threadIdx.x] = thr_half[gi];
        s_lab[threadIdx.x] = gt_labels[gi];
    }
    __syncthreads();

    const float* sc = pred_scores + (size_t)b * N_ * 10;
    float4 pr = ((const float4*)priors)[n];
    float2 v2p = pxz[(size_t)b * N_ + n];
    float px = v2p.x;
    float pz = v2p.y;

    // init = g 0 (argmin over all-INF costs returns index 0)
    float iouC = iou_pair(px, pz, s_g3x[0], s_g3z[0]);
    float costC = INF_;
    int   labC = s_lab[0];

    float iouM = 0.0f, costM = 3.0e38f;
    int   labM = 0, argM = 0;
    u64 mmatch = 0;

    u64 m = mask64[t];
    while (m) {
        int g = __ffsll(m) - 1;
        m &= m - 1;
        float gcx = s_gcx[g], gcy = s_gcy[g];
        float g3x = s_g3x[g], g3z = s_g3z[g];
        float padg = s_pad[g];
        int   labg = s_lab[g];
        float th = s_thr[g];
        float ps = sc[n * 10 + labg];
        float iou = iou_pair(px, pz, g3x, g3z);
        float c = cost_pair(pr.x, pr.y, pr.z, pr.w, ps, gcx, gcy, padg, iou);
        if (c < costC) { costC = c; iouC = iou; labC = labg; }
        if (c <= th * padg) {
            mmatch |= 1ull << g;
            if (c < costM) { costM = c; iouM = iou; labM = labg; argM = g; }
        }
    }
    int cm = __popcll(mmatch);
    bool matched = cm > 0;
    u64 outm = (cm > 1) ? (1ull << argM) : mmatch;
    float metric = matched ? iouM : iouC;
    float olab = matched ? (float)labM
                         : ((iouC < 1e-7f) ? (float)NCLS : (float)labC);

    float* out_lab = out;
    float* out_w   = out + (size_t)B_ * N_;
    float* out_met = out + (size_t)2 * B_ * N_;
    float* out_mat = out + (size_t)3 * B_ * N_;
    out_lab[t] = olab;
    out_w[t]   = 1.0f;
    out_met[t] = metric;
    s_words[threadIdx.x] = outm;
    __syncthreads();

    // Phase 2: expand 256 words -> 256 rows x 64 floats, coalesced.
    int q  = threadIdx.x & 3;                  // 16-col quarter
    int r0 = threadIdx.x >> 2;                 // base row 0..63
    size_t rowbase = (size_t)b * N_ + n0b;
#pragma unroll
    for (int it = 0; it < 4; ++it) {
        int row = r0 + (it << 6);
        u64 wv = s_words[row];
        u32 bits = (u32)(wv >> (q * 16)) & 0xffffu;
        float* dst = out_mat + (rowbase + row) * 64 + q * 16;
#pragma unroll
        for (int jj = 0; jj < 4; ++jj) {
            float4 f;
            f.x = (bits >> (jj * 4 + 0)) & 1u ? 1.0f : 0.0f;
            f.y = (bits >> (jj * 4 + 1)) & 1u ? 1.0f : 0.0f;
            f.z = (bits >> (jj * 4 + 2)) & 1u ? 1.0f : 0.0f;
            f.w = (bits >> (jj * 4 + 3)) & 1u ? 1.0f : 0.0f;
            ((float4*)dst)[jj] = f;
        }
    }
}

extern "C" void kernel_launch(void* const* d_in, const int* in_sizes, int n_in,
                              void* d_out, int out_size, void* d_ws, size_t ws_size,
                              hipStream_t stream)
{
    const float* pred_bboxes = (const float*)d_in[0];
    const float* pred_scores = (const float*)d_in[1];
    const float* priors      = (const float*)d_in[2];
    const int*   gt_labels   = (const int*)d_in[3];
    const float* gt_bboxes   = (const float*)d_in[4];
    const float* gt_center   = (const float*)d_in[5];
    const float* gt_b3d      = (const float*)d_in[6];
    const float* pad_flag    = (const float*)d_in[7];
    float* out = (float*)d_out;

    // ws layout (bytes):
    char* ws = (char*)d_ws;
    u64* mask64   = (u64*)ws;                              // 131072*8 = 1048576
    u64* bitmapT  = (u64*)(ws + 1048576);                  // 256*512*8 = 1048576
    float2* pxz   = (float2*)(ws + 2097152);               // 131072*8 = 1048576
    float* iou13  = (float*)(ws + 3145728);                // 512*416*4 = 851968
    float* thr_half = (float*)(ws + 3145728 + 851968);     // 512*4

    kP<<<576, 256, 0, stream>>>(priors, gt_bboxes, pad_flag, pred_bboxes,
                                mask64, bitmapT, pxz);
    k1b<<<4096, 256, 0, stream>>>(pxz, gt_b3d, iou13);
    k1c<<<512, 256, 0, stream>>>(iou13, bitmapT, priors, pxz,
                                 pred_scores, gt_labels, gt_center, gt_b3d,
                                 pad_flag, thr_half);
    k2<<<512, 256, 0, stream>>>(priors, pxz, pred_scores, gt_labels,
                                gt_center, gt_b3d, pad_flag,
                                thr_half, mask64, out);
}